// Round 8
// baseline (114.554 us; speedup 1.0000x reference)
//
#include <hip/hip_runtime.h>
#include <stdint.h>

#define H 240
#define W 320
#define NPIX (H * W)          // 76800
#define NCLS 10
#define TILE 16               // columns per vote block (lane = entry-group x column)
#define HPAD 241              // hist leading dim: (241+s)%32 = 17+s bank stride
#define BIN_BITS 20
#define BIN_MASK 0xFFFFFu

// d_ws layout (bytes):
//   [0,40)    uint32 cls_count[10]   (= cmask.sum per class)
//   [64,144)  u64    best[10]        (atomicMax key: (count<<20)|(MASK-bin))
//   [192,232) uint32 icnt[10]
//   [256,296) float  dsum[10]
//   [320,324) uint32 done            (last-block counter for fused finalize)
//   [512,...) uint2  list[10][NPIX]  ({x|y<<16, slope bits})

__global__ void k_init(uint32_t* ws) {
    int i = threadIdx.x;
    if (i < 128) ws[i] = 0;   // zero first 512 bytes (all counters/keys/done)
}

// Hierarchical-aggregated compaction: LDS per-class counters -> one global
// atomicAdd per class per block (3K total vs 70K contended in R1).
__global__ __launch_bounds__(256) void k_compact(const int* __restrict__ label,
                                                 const float* __restrict__ cm,
                                                 uint32_t* __restrict__ cls_cnt,
                                                 uint2* __restrict__ list) {
    __shared__ uint32_t lcnt[NCLS];
    __shared__ uint32_t lbase[NCLS];
    int p = blockIdx.x * 256 + threadIdx.x;   // NPIX % 256 == 0, no OOB
    if (threadIdx.x < NCLS) lcnt[threadIdx.x] = 0;
    __syncthreads();

    int l = label[p];
    bool match = (l >= 1 && l <= NCLS);
    int cls = l - 1;
    uint32_t li = 0;
    if (match) li = atomicAdd(&lcnt[cls], 1u);
    __syncthreads();

    if (threadIdx.x < NCLS) {
        uint32_t c = lcnt[threadIdx.x];
        lbase[threadIdx.x] = c ? atomicAdd(&cls_cnt[threadIdx.x], c) : 0u;
    }
    __syncthreads();

    if (match) {
        float dirx = cm[(cls * 3 + 0) * NPIX + p];
        float diry = cm[(cls * 3 + 1) * NPIX + p];
        float slope = diry / dirx;
        int y = p / W, x = p - y * W;
        uint2 e;
        e.x = (uint32_t)(x | (y << 16));
        e.y = __float_as_uint(slope);
        list[cls * NPIX + lbase[cls] + li] = e;
    }
}

// Transposed vote: lane = (entry-group g=lane/16, column cit=lane%16).
// Each wave-instr processes 4 entries x 16 columns -> every lane writes a
// DIFFERENT column's histogram: same-address LDS-atomic serialization capped
// at 4-way by construction (free-ish per m136), no ballot machinery. List
// load per wave = 4 consecutive uint2 = one 32B segment (broadcast).
__global__ __launch_bounds__(1024) void k_vote(const uint32_t* __restrict__ cls_cnt,
                                               const uint2* __restrict__ list,
                                               unsigned long long* __restrict__ best) {
    int cls = blockIdx.y;
    int x0 = blockIdx.x * TILE;
    __shared__ uint32_t hist[TILE * HPAD];
    __shared__ unsigned long long wred[16];
    int tid = threadIdx.x;
    for (int i = tid; i < TILE * HPAD; i += 1024) hist[i] = 0;
    __syncthreads();

    int n = (int)cls_cnt[cls];
    const uint2* lst = list + cls * NPIX;
    int wave = tid >> 6, lane = tid & 63;
    int g = lane >> 4, cit = lane & 15;
    float colf = (float)(x0 + cit);
    uint32_t* hcol = &hist[cit * HPAD];
    // Round r: 16 waves x 4 groups cover 64 consecutive entries.
    for (int i = wave * 4 + g; i < n; i += 64) {
        uint2 e = lst[i];
        float slope = __uint_as_float(e.y);
        float xf = (float)(e.x & 0xFFFFu);
        float yf = (float)(e.x >> 16);
        float r = rintf(yf + slope * (colf - xf));  // half-to-even == jnp.round
        // float-domain bounds check: NaN/inf/huge all fail, matching the
        // reference's (y_idx>=0)&(y_idx<H).
        if (r >= 0.0f && r <= 239.0f) atomicAdd(&hcol[(int)r], 1u);
    }
    __syncthreads();

    // scan TILE*H bins -> key = (count<<20)|(MASK-bin); max key == argmax with
    // lowest-flat-bin tie-break (matches jnp.argmax).
    unsigned long long k = 0;
    for (int i = tid; i < TILE * H; i += 1024) {
        int c = i / H, y = i - c * H;
        uint32_t v = hist[c * HPAD + y];
        uint32_t bin = (uint32_t)(y * W + x0 + c);
        unsigned long long key =
            ((unsigned long long)v << BIN_BITS) | (unsigned long long)(BIN_MASK - bin);
        if (key > k) k = key;
    }
#pragma unroll
    for (int off = 32; off > 0; off >>= 1) {
        unsigned long long o = __shfl_down(k, off);
        if (o > k) k = o;
    }
    if (lane == 0) wred[wave] = k;
    __syncthreads();
    if (tid == 0) {
        unsigned long long kk = wred[0];
#pragma unroll
        for (int w = 1; w < 16; ++w) if (wred[w] > kk) kk = wred[w];
        atomicMax(&best[cls], kk);
    }
}

// Single-pass inlier over ALL classes (each pixel contributes only to its own
// label's class) + fused finalize via deadlock-free last-block-done pattern.
__global__ __launch_bounds__(256) void k_inlier_final(
    const int* __restrict__ label, const float* __restrict__ cm,
    const uint32_t* __restrict__ cls_cnt,
    const unsigned long long* __restrict__ best,
    uint32_t* __restrict__ icnt, float* __restrict__ dsum,
    uint32_t* __restrict__ done, float* __restrict__ out) {
    __shared__ float scx[NCLS], scy[NCLS];
    __shared__ uint32_t scnt[NCLS];
    __shared__ float ssum[NCLS];
    __shared__ int slast;
    int tid = threadIdx.x;
    if (tid < NCLS) {
        unsigned long long key = best[tid];
        uint32_t bin = BIN_MASK - (uint32_t)(key & BIN_MASK);
        scx[tid] = (float)(bin % W);
        scy[tid] = (float)(bin / W);
        scnt[tid] = 0u;
        ssum[tid] = 0.0f;
    }
    __syncthreads();

    int p = blockIdx.x * 256 + tid;           // 300 blocks * 256 = NPIX
    int l = label[p];
    if (l >= 1 && l <= NCLS) {
        int cls = l - 1;
        int y = p / W, x = p - y * W;
        float disx = (float)x - scx[cls];
        float disy = (float)y - scy[cls];
        float dn = sqrtf(disx * disx + disy * disy);
        if (dn > 0.0f) {                      // dn==0 -> NaN dot in ref -> excluded
            float c0 = cm[(cls * 3 + 0) * NPIX + p];
            float c1 = cm[(cls * 3 + 1) * NPIX + p];
            float dot = fabsf((disx / dn) * c0 + (disy / dn) * c1);
            if (dot >= 0.9f) {
                atomicAdd(&scnt[cls], 1u);
                atomicAdd(&ssum[cls], cm[(cls * 3 + 2) * NPIX + p]);
            }
        }
    }
    __syncthreads();

    if (tid < NCLS) {
        if (scnt[tid]) atomicAdd(&icnt[tid], scnt[tid]);
        if (ssum[tid] != 0.0f) atomicAdd(&dsum[tid], ssum[tid]);
    }
    if (tid == 0) {
        __threadfence();                      // publish our atomics device-wide
        uint32_t d = atomicAdd(done, 1u);
        slast = (d == (uint32_t)(gridDim.x - 1)) ? 1 : 0;
    }
    __syncthreads();

    if (slast && tid < NCLS) {
        // device-coherent totals via atomic fetch-add-0 (bypass stale L1)
        uint32_t tc = atomicAdd(&icnt[tid], 0u);
        float td = atomicAdd(&dsum[tid], 0.0f);
        unsigned long long key = best[tid];
        uint32_t hv = (uint32_t)(key >> BIN_BITS);
        bool trig = (cls_cnt[tid] >= 500u) && (hv > 500u);
        float c = (float)tc;
        float dm = (c > 0.0f) ? (td / fmaxf(c, 1.0f)) : __builtin_nanf("");
        out[tid * 2 + 0] = trig ? scx[tid] : 0.0f;
        out[tid * 2 + 1] = trig ? scy[tid] : 0.0f;
        out[2 * NCLS + tid] = trig ? dm : 0.0f;
    }
}

extern "C" void kernel_launch(void* const* d_in, const int* in_sizes, int n_in,
                              void* d_out, int out_size, void* d_ws, size_t ws_size,
                              hipStream_t stream) {
    const int* label = (const int*)d_in[0];
    const float* cm = (const float*)d_in[1];
    float* out = (float*)d_out;
    char* ws = (char*)d_ws;

    uint32_t* cls_cnt = (uint32_t*)(ws + 0);
    unsigned long long* best = (unsigned long long*)(ws + 64);
    uint32_t* icnt = (uint32_t*)(ws + 192);
    float* dsum = (float*)(ws + 256);
    uint32_t* done = (uint32_t*)(ws + 320);
    uint2* list = (uint2*)(ws + 512);

    k_init<<<1, 128, 0, stream>>>((uint32_t*)ws);
    k_compact<<<NPIX / 256, 256, 0, stream>>>(label, cm, cls_cnt, list);
    k_vote<<<dim3(W / TILE, NCLS), 1024, 0, stream>>>(cls_cnt, list, best);
    k_inlier_final<<<NPIX / 256, 256, 0, stream>>>(label, cm, cls_cnt, best,
                                                   icnt, dsum, done, out);
}